// Round 3
// baseline (134.755 us; speedup 1.0000x reference)
//
#include <hip/hip_runtime.h>

// Depthwise causal conv1d with learnable hidden-state prefix.
// x: [B, D, L] f32; weight: [D,1,4] f32; bias: [D] f32; init_state: [D,3] f32
// out: [B, D, L+3] f32
//
// out[b,d,t] = bias[d] + sum_{j=0..3} w[d,j] * xm(t-3+j)
//   xm(i) = init_state[d, i+3]  for -3 <= i < 0
//         = x[b,d,i]            for 0 <= i < L
//         = 0                   for i >= L
//
// Fully vectorized: aligned float4 loads AND aligned float4 stores.
// Out-row byte stride 16396 == 12 (mod 16); phase pad = row & 3 makes
// (row*16396 + (pad+4c)*4) % 16 == 0, so storing chunks at t0 = pad + 4c
// is 16B-aligned for every row. Each row leaves pad head + (3-pad) tail
// scalar elements (3 total), handled by 3 lanes of the seg==3 block.

namespace {

constexpr int D = 4096;
constexpr int L = 4096;
constexpr int LOUT = L + 3;   // 4099

__global__ __launch_bounds__(256) void causal_conv1d_kernel(
    const float* __restrict__ x,
    const float* __restrict__ w,      // [D,4]
    const float* __restrict__ bias,   // [D]
    const float* __restrict__ init,   // [D,3]
    float* __restrict__ out)
{
    unsigned bid = blockIdx.x;
    unsigned row = bid >> 2;          // 4 segments (blocks) per row
    unsigned seg = bid & 3u;
    unsigned d   = row & (unsigned)(D - 1);
    unsigned pad = row & 3u;          // store-alignment phase for this row

    const float* xr   = x + (size_t)row * L;
    float*       outr = out + (size_t)row * LOUT;

    // block-uniform -> scalar loads
    float w0 = w[d*4+0], w1 = w[d*4+1], w2 = w[d*4+2], w3 = w[d*4+3];
    float b  = bias[d];

    unsigned c = seg * 256u + threadIdx.x;   // vector chunk index in [0,1024)
    int q = (int)(c << 2);                   // aligned x offset

    // cur: x[q .. q+3]
    float4 C = *reinterpret_cast<const float4*>(xr + q);

    // prev: x[q-4 .. q-1]; at c==0 splice learnable state (x[-3..-1] = init)
    float4 P;
    if (c == 0u) {
        P = make_float4(0.f, init[d*3+0], init[d*3+1], init[d*3+2]);
    } else {
        P = *reinterpret_cast<const float4*>(xr + q - 4);
    }

    // next: x[q+4 .. q+7]; needed only when pad>0. At c==1023 it's past the
    // row end -> zeros (xm(i>=L) = 0).
    float4 N = make_float4(0.f, 0.f, 0.f, 0.f);
    if (pad != 0u && c != 1023u) {
        N = *reinterpret_cast<const float4*>(xr + q + 4);
    }

    // window v[0..6] = xm(t0-3 .. t0+3), t0 = pad + q  (pad is block-uniform)
    float v0, v1, v2, v3, v4, v5, v6;
    if (pad == 0u)      { v0=P.y; v1=P.z; v2=P.w; v3=C.x; v4=C.y; v5=C.z; v6=C.w; }
    else if (pad == 1u) { v0=P.z; v1=P.w; v2=C.x; v3=C.y; v4=C.z; v5=C.w; v6=N.x; }
    else if (pad == 2u) { v0=P.w; v1=C.x; v2=C.y; v3=C.z; v4=C.w; v5=N.x; v6=N.y; }
    else                { v0=C.x; v1=C.y; v2=C.z; v3=C.w; v4=N.x; v5=N.y; v6=N.z; }

    float4 o;
    o.x = b + w0*v0 + w1*v1 + w2*v2 + w3*v3;
    o.y = b + w0*v1 + w1*v2 + w2*v3 + w3*v4;
    o.z = b + w0*v2 + w1*v3 + w2*v4 + w3*v5;
    o.w = b + w0*v3 + w1*v4 + w2*v5 + w3*v6;
    *reinterpret_cast<float4*>(outr + pad + q) = o;   // 16B-aligned by construction

    // 3 leftover scalars per row: head t in [0,pad), tail t in [pad+4096, 4099)
    if (seg == 3u && threadIdx.x < 3u) {
        int e = (int)threadIdx.x;
        int t = (e < (int)pad) ? e : (L + e);
        auto xm = [&](int i) -> float {
            if (i < 0) return init[d*3 + (i + 3)];
            if (i < L) return xr[i];
            return 0.f;
        };
        outr[t] = b + w0*xm(t-3) + w1*xm(t-2) + w2*xm(t-1) + w3*xm(t);
    }
}

} // namespace

extern "C" void kernel_launch(void* const* d_in, const int* in_sizes, int n_in,
                              void* d_out, int out_size, void* d_ws, size_t ws_size,
                              hipStream_t stream) {
    const float* x    = (const float*)d_in[0];  // [B,D,L]
    const float* w    = (const float*)d_in[1];  // [D,1,4]
    const float* bias = (const float*)d_in[2];  // [D]
    const float* init = (const float*)d_in[3];  // [D,3]
    float* out = (float*)d_out;                 // [B,D,L+3]

    unsigned rows = (unsigned)(in_sizes[0] / L);   // B*D = 16384
    unsigned blocks = rows * 4u;                   // 65536 blocks x 256 thr
    causal_conv1d_kernel<<<blocks, 256, 0, stream>>>(x, w, bias, init, out);
}

// Round 4
// 108.890 us; speedup vs baseline: 1.2375x; 1.2375x over previous
//
#include <hip/hip_runtime.h>

// Depthwise causal conv1d with learnable hidden-state prefix.
// x: [B, D, L] f32; weight: [D,1,4] f32; bias: [D] f32; init_state: [D,3] f32
// out: [B, D, L+3] f32
//
// out[b,d,t] = bias[d] + sum_{j=0..3} w[d,j] * xm(t-3+j)
//   xm(i) = init_state[d, i+3]  for -3 <= i < 0
//         = x[b,d,i]            for 0 <= i < L
//         = 0                   for i >= L
//
// Copy-identical VMEM: each lane loads its own aligned float4 of x exactly
// once and stores one aligned float4 of out; the 3 neighbor values come from
// wave shuffles (register traffic, no L1/L2 redundancy). Stores are 16B
// aligned via the per-row phase pad = row & 3 (row byte stride 16396 == 12
// mod 16, and 4*(row*4099 + pad) % 16 == 0).

namespace {

constexpr int D = 4096;
constexpr int L = 4096;
constexpr int LOUT = L + 3;   // 4099

__global__ __launch_bounds__(256) void causal_conv1d_kernel(
    const float* __restrict__ x,
    const float* __restrict__ w,      // [D,4]
    const float* __restrict__ bias,   // [D]
    const float* __restrict__ init,   // [D,3]
    float* __restrict__ out)
{
    unsigned row  = blockIdx.x;            // one block per row
    unsigned d    = row & (unsigned)(D - 1);
    unsigned pad  = row & 3u;              // store-alignment phase
    unsigned lane = threadIdx.x & 63u;

    const float* xr   = x + (size_t)row * L;
    float*       outr = out + (size_t)row * LOUT;

    // block-uniform -> scalar loads
    float w0 = w[d*4+0], w1 = w[d*4+1], w2 = w[d*4+2], w3 = w[d*4+3];
    float b  = bias[d];

#pragma unroll
    for (int k = 0; k < 4; ++k) {
        unsigned c = (unsigned)k * 256u + threadIdx.x;   // chunk in [0,1024)
        int q = (int)(c << 2);
        float4 C = *reinterpret_cast<const float4*>(xr + q);  // own 16B, once

        float v0, v1, v2, v3, v4, v5, v6;   // xm(t0-3 .. t0+3), t0 = pad + q

        if (pad == 0u) {
            // need x[q-3..q-1] from left neighbor lane
            float lm3 = __shfl_up(C.y, 1);
            float lm2 = __shfl_up(C.z, 1);
            float lm1 = __shfl_up(C.w, 1);
            if (lane == 0u) {
                if (c == 0u) {
                    lm3 = init[d*3+0]; lm2 = init[d*3+1]; lm1 = init[d*3+2];
                } else {
                    float4 P = *reinterpret_cast<const float4*>(xr + q - 4);
                    lm3 = P.y; lm2 = P.z; lm1 = P.w;
                }
            }
            v0=lm3; v1=lm2; v2=lm1; v3=C.x; v4=C.y; v5=C.z; v6=C.w;
        } else if (pad == 1u) {
            float lm2 = __shfl_up(C.z, 1);
            float lm1 = __shfl_up(C.w, 1);
            float rp4 = __shfl_down(C.x, 1);
            if (lane == 0u) {
                if (c == 0u) {
                    lm2 = init[d*3+1]; lm1 = init[d*3+2];
                } else {
                    float4 P = *reinterpret_cast<const float4*>(xr + q - 4);
                    lm2 = P.z; lm1 = P.w;
                }
            }
            if (lane == 63u) {
                rp4 = (c == 1023u) ? 0.f : xr[q + 4];
            }
            v0=lm2; v1=lm1; v2=C.x; v3=C.y; v4=C.z; v5=C.w; v6=rp4;
        } else if (pad == 2u) {
            float lm1 = __shfl_up(C.w, 1);
            float rp4 = __shfl_down(C.x, 1);
            float rp5 = __shfl_down(C.y, 1);
            if (lane == 0u) {
                lm1 = (c == 0u) ? init[d*3+2]
                                : xr[q - 1];
            }
            if (lane == 63u) {
                if (c == 1023u) { rp4 = 0.f; rp5 = 0.f; }
                else {
                    float2 N = *reinterpret_cast<const float2*>(xr + q + 4);
                    rp4 = N.x; rp5 = N.y;
                }
            }
            v0=lm1; v1=C.x; v2=C.y; v3=C.z; v4=C.w; v5=rp4; v6=rp5;
        } else { // pad == 3
            float rp4 = __shfl_down(C.x, 1);
            float rp5 = __shfl_down(C.y, 1);
            float rp6 = __shfl_down(C.z, 1);
            if (lane == 63u) {
                if (c == 1023u) { rp4 = 0.f; rp5 = 0.f; rp6 = 0.f; }
                else {
                    float4 N = *reinterpret_cast<const float4*>(xr + q + 4);
                    rp4 = N.x; rp5 = N.y; rp6 = N.z;
                }
            }
            v0=C.x; v1=C.y; v2=C.z; v3=C.w; v4=rp4; v5=rp5; v6=rp6;
        }

        float4 o;
        o.x = b + w0*v0 + w1*v1 + w2*v2 + w3*v3;
        o.y = b + w0*v1 + w1*v2 + w2*v3 + w3*v4;
        o.z = b + w0*v2 + w1*v3 + w2*v4 + w3*v5;
        o.w = b + w0*v3 + w1*v4 + w2*v5 + w3*v6;
        *reinterpret_cast<float4*>(outr + pad + q) = o;   // 16B-aligned
    }

    // 3 leftover scalars per row: head t in [0,pad), tail t in [pad+L, L+3)
    if (threadIdx.x < 3u) {
        int e = (int)threadIdx.x;
        int t = (e < (int)pad) ? e : (L + e);
        auto xm = [&](int i) -> float {
            if (i < 0) return init[d*3 + (i + 3)];
            if (i < L) return xr[i];
            return 0.f;
        };
        outr[t] = b + w0*xm(t-3) + w1*xm(t-2) + w2*xm(t-1) + w3*xm(t);
    }
}

} // namespace

extern "C" void kernel_launch(void* const* d_in, const int* in_sizes, int n_in,
                              void* d_out, int out_size, void* d_ws, size_t ws_size,
                              hipStream_t stream) {
    const float* x    = (const float*)d_in[0];  // [B,D,L]
    const float* w    = (const float*)d_in[1];  // [D,1,4]
    const float* bias = (const float*)d_in[2];  // [D]
    const float* init = (const float*)d_in[3];  // [D,3]
    float* out = (float*)d_out;                 // [B,D,L+3]

    unsigned rows = (unsigned)(in_sizes[0] / L);   // B*D = 16384
    causal_conv1d_kernel<<<rows, 256, 0, stream>>>(x, w, bias, init, out);
}

// Round 5
// 84.602 us; speedup vs baseline: 1.5928x; 1.2871x over previous
//
#include <hip/hip_runtime.h>

// Depthwise causal conv1d with learnable hidden-state prefix.
// x: [B, D, L] f32; weight: [D,1,4] f32; bias: [D] f32; init_state: [D,3] f32
// out: [B, D, L+3] f32
//
// out[b,d,t] = bias[d] + sum_{j=0..3} w[d,j] * xm(t-3+j)
//   xm(i) = init_state[d, i+3]  for -3 <= i < 0
//         = x[b,d,i]            for 0 <= i < L
//         = 0                   for i >= L
//
// Round-1 winner (lane-dense loads+stores; overlapping loads MSHR-coalesce)
// + NONTEMPORAL stores: the out stream (269MB) can never fit the 256MB
// Infinity Cache, so mark it no-allocate; x (256MB) then stays L3-resident
// across graph replays and HBM carries only the write stream.

namespace {

constexpr int D = 4096;
constexpr int L = 4096;
constexpr int LOUT = L + 3;   // 4099

__global__ __launch_bounds__(256) void causal_conv1d_kernel(
    const float* __restrict__ x,
    const float* __restrict__ w,      // [D,4]
    const float* __restrict__ bias,   // [D]
    const float* __restrict__ init,   // [D,3]
    float* __restrict__ out)
{
    unsigned bid = blockIdx.x;
    unsigned row = bid >> 2;          // 4 segments per row
    unsigned seg = bid & 3u;
    unsigned d   = row & (D - 1);

    const float* xr  = x + (size_t)row * L;
    float*       outr = out + (size_t)row * LOUT;

    // block-uniform -> scalar loads
    float w0 = w[d * 4 + 0];
    float w1 = w[d * 4 + 1];
    float w2 = w[d * 4 + 2];
    float w3 = w[d * 4 + 3];
    float b  = bias[d];

    unsigned tb = seg * 1024u + threadIdx.x;

#pragma unroll
    for (int k = 0; k < 4; ++k) {
        int t = (int)tb + k * 256;    // t <= 4095 always here
        float v0, v1, v2, v3;
        if (t >= 3) {
            // interior fast path: 4 dense dword loads, MSHR-coalesced
            v0 = xr[t - 3];
            v1 = xr[t - 2];
            v2 = xr[t - 1];
            v3 = xr[t];
        } else {
            // t in {0,1,2}: splice learnable state (3 lanes of one wave total)
            v0 = init[d * 3 + t];                            // idx t-3 -> init[t]
            v1 = (t - 2 >= 0) ? xr[t - 2] : init[d * 3 + t + 1];
            v2 = (t - 1 >= 0) ? xr[t - 1] : init[d * 3 + t + 2];
            v3 = xr[t];
        }
        float o = b + w0 * v0 + w1 * v1 + w2 * v2 + w3 * v3;
        __builtin_nontemporal_store(o, &outr[t]);
    }

    // tail: t = 4096..4098, window runs past end of x (zeros)
    if (seg == 3u && threadIdx.x < 3u) {
        int t  = L + (int)threadIdx.x;
        int i0 = t - 3;               // 4093..4095, always valid
        float acc = b + w0 * xr[i0];
        if (i0 + 1 < L) acc += w1 * xr[i0 + 1];
        if (i0 + 2 < L) acc += w2 * xr[i0 + 2];
        __builtin_nontemporal_store(acc, &outr[t]);
    }
}

} // namespace

extern "C" void kernel_launch(void* const* d_in, const int* in_sizes, int n_in,
                              void* d_out, int out_size, void* d_ws, size_t ws_size,
                              hipStream_t stream) {
    const float* x    = (const float*)d_in[0];  // [B,D,L]
    const float* w    = (const float*)d_in[1];  // [D,1,4]
    const float* bias = (const float*)d_in[2];  // [D]
    const float* init = (const float*)d_in[3];  // [D,3]
    float* out = (float*)d_out;                 // [B,D,L+3]

    unsigned rows = (unsigned)(in_sizes[0] / L);   // B*D = 16384
    unsigned blocks = rows * 4u;                   // 65536
    causal_conv1d_kernel<<<blocks, 256, 0, stream>>>(x, w, bias, init, out);
}